// Round 1
// baseline (2789.769 us; speedup 1.0000x reference)
//
#include <hip/hip_runtime.h>

// DiT block fused pipeline for MI355X (gfx950).
// B=8 T=1024 D=1152 H=16 hd=72 E=4.
#define B_ 8
#define T_ 1024
#define D_ 1152
#define H_ 16
#define HD_ 72
#define M_ (B_*T_)      // 8192 rows
#define D3_ (3*D_)      // 3456
#define D4_ (4*D_)      // 4608
#define D6_ (6*D_)      // 6912

typedef unsigned short u16;
typedef __attribute__((ext_vector_type(4))) float f32x4;
typedef __attribute__((ext_vector_type(4))) unsigned int u32x4;

__device__ __forceinline__ u16 f2b(float f) {           // fp32 -> bf16 RNE
  union { float f; unsigned u; } v; v.f = f;
  unsigned r = v.u + 0x7FFFu + ((v.u >> 16) & 1u);
  return (u16)(r >> 16);
}
__device__ __forceinline__ float b2f(u16 h) {
  union { unsigned u; float f; } v; v.u = ((unsigned)h) << 16;
  return v.f;
}

// MFMA via inline asm: avoids builtin operand-type ambiguity (short8 vs __bf16x8).
// D==C tied ("+v"); a/b are 4 VGPRs holding 8 bf16 each.
__device__ __forceinline__ void mfma16x16x32(f32x4& d, u32x4 a, u32x4 b) {
  asm("v_mfma_f32_16x16x32_bf16 %0, %1, %2, %0" : "+v"(d) : "v"(a), "v"(b));
}

__device__ __forceinline__ void load_lds16(const void* g, void* l) {
  __builtin_amdgcn_global_load_lds((const __attribute__((address_space(1))) void*)g,
                                   (__attribute__((address_space(3))) void*)l, 16, 0, 0);
}

// ---------------- weight transpose + bf16 convert:  W[K][N] f32 -> Wt[N][K] bf16
__global__ __launch_bounds__(256) void wconv_kernel(const float* __restrict__ W,
                                                    u16* __restrict__ Wt, int K, int N) {
  __shared__ float tile[32][33];
  int k0 = blockIdx.y * 32, n0 = blockIdx.x * 32;
  int tx = threadIdx.x, ty = threadIdx.y;   // 32 x 8
  #pragma unroll
  for (int i = 0; i < 32; i += 8)
    tile[ty + i][tx] = W[(size_t)(k0 + ty + i) * N + n0 + tx];
  __syncthreads();
  #pragma unroll
  for (int i = 0; i < 32; i += 8)
    Wt[(size_t)(n0 + ty + i) * K + k0 + tx] = f2b(tile[tx][ty + i]);
}

// ---------------- mods = silu(c) @ ada_w + ada_b   -> [B][6D] f32
__global__ __launch_bounds__(256) void mods_kernel(const float* __restrict__ c,
                                                   const float* __restrict__ ada_w,
                                                   const float* __restrict__ ada_b,
                                                   float* __restrict__ mods) {
  int b = blockIdx.x;
  int j = blockIdx.y * 256 + threadIdx.x;
  __shared__ float sc[D_];
  for (int d = threadIdx.x; d < D_; d += 256) {
    float v = c[b * D_ + d];
    sc[d] = v / (1.f + __expf(-v));
  }
  __syncthreads();
  float acc = ada_b[j];
  for (int k = 0; k < D_; ++k) acc += sc[k] * ada_w[(size_t)k * D6_ + j];
  mods[b * D6_ + j] = acc;
}

// ---------------- LayerNorm + modulate -> bf16 activations
__global__ __launch_bounds__(256) void ln_mod_kernel(const float* __restrict__ x,
                                                     const float* __restrict__ mods,
                                                     int shift_off, int scale_off,
                                                     u16* __restrict__ y) {
  int row = blockIdx.x;          // 0..8191
  int b = row >> 10;
  int tid = threadIdx.x;
  const float* xr = x + (size_t)row * D_;
  float s = 0.f, ss = 0.f;
  for (int d = tid; d < D_; d += 256) { float v = xr[d]; s += v; ss += v * v; }
  #pragma unroll
  for (int o = 32; o > 0; o >>= 1) { s += __shfl_down(s, o); ss += __shfl_down(ss, o); }
  __shared__ float red[2][4];
  int wid = tid >> 6, lane = tid & 63;
  if (lane == 0) { red[0][wid] = s; red[1][wid] = ss; }
  __syncthreads();
  __shared__ float stat[2];
  if (tid == 0) {
    float S = red[0][0] + red[0][1] + red[0][2] + red[0][3];
    float SS = red[1][0] + red[1][1] + red[1][2] + red[1][3];
    float mu = S * (1.f / D_);
    float var = SS * (1.f / D_) - mu * mu;
    stat[0] = mu; stat[1] = rsqrtf(var + 1e-6f);
  }
  __syncthreads();
  float mu = stat[0], inv = stat[1];
  const float* sh = mods + b * D6_ + shift_off;
  const float* scl = mods + b * D6_ + scale_off;
  u16* yr = y + (size_t)row * D_;
  for (int d = tid; d < D_; d += 256) {
    float v = (xr[d] - mu) * inv;
    yr[d] = f2b(v * (1.f + scl[d]) + sh[d]);
  }
}

// ---------------- bf16 MFMA GEMM, 128x128x32 tiles, m97 structure.
// A[M][K] bf16 row-major, Bt[N][K] bf16 row-major (i.e. B transposed).
// EPI: 0 = acc+bias -> bf16 ; 1 = gelu_tanh(acc+bias) -> bf16 ;
//      2 = resid + mod*(acc+bias) -> f32
template<int EPI>
__global__ __launch_bounds__(256, 2)
void gemm_kernel(const u16* __restrict__ A, const u16* __restrict__ Bt,
                 const float* __restrict__ bias, const float* __restrict__ resid,
                 const float* __restrict__ mods, int mod_off,
                 void* __restrict__ Cout, int N, int K) {
  __shared__ __align__(16) u16 As[128 * 32];
  __shared__ __align__(16) u16 Bs[128 * 32];
  int bm = blockIdx.x, bn = blockIdx.y;
  int tid = threadIdx.x;
  int lane = tid & 63;
  int wid = tid >> 6;
  int wm = wid >> 1, wn = wid & 1;          // 2x2 wave grid, each wave 64x64
  int fr = lane & 15, fq = lane >> 4;

  f32x4 acc[4][4] = {};

  const char* Ab = (const char*)A + (size_t)bm * 128 * K * 2;
  const char* Bb = (const char*)Bt + (size_t)bn * 128 * K * 2;
  int o0 = tid * 16;                        // per-lane byte offset in 8KB tile
  int r0 = o0 >> 6, cb = o0 & 63;           // tile row / byte-in-row
  const char* Ag0 = Ab + (size_t)r0 * (K * 2) + cb;
  const char* Ag1 = Ab + (size_t)(r0 + 64) * (K * 2) + cb;
  const char* Bg0 = Bb + (size_t)r0 * (K * 2) + cb;
  const char* Bg1 = Bb + (size_t)(r0 + 64) * (K * 2) + cb;
  u16* Al0 = As + (o0 >> 1);
  u16* Al1 = As + ((o0 + 4096) >> 1);
  u16* Bl0 = Bs + (o0 >> 1);
  u16* Bl1 = Bs + ((o0 + 4096) >> 1);

  const u32x4* pA = ((const u32x4*)As) + (wm * 64 + fr) * 4 + fq;
  const u32x4* pB = ((const u32x4*)Bs) + (wn * 64 + fr) * 4 + fq;

  for (int k0 = 0; k0 < K; k0 += 32) {
    size_t kb = (size_t)k0 * 2;
    load_lds16(Ag0 + kb, Al0);
    load_lds16(Ag1 + kb, Al1);
    load_lds16(Bg0 + kb, Bl0);
    load_lds16(Bg1 + kb, Bl1);
    __syncthreads();
    u32x4 af[4], bfr[4];
    #pragma unroll
    for (int m = 0; m < 4; ++m) af[m] = pA[m * 64];
    #pragma unroll
    for (int n = 0; n < 4; ++n) bfr[n] = pB[n * 64];
    #pragma unroll
    for (int m = 0; m < 4; ++m)
      #pragma unroll
      for (int n = 0; n < 4; ++n)
        mfma16x16x32(acc[m][n], af[m], bfr[n]);
    __syncthreads();
  }

  // epilogue: C/D layout col=lane&15 (fr), row=4*(lane>>4)+j (fq*4+j)   [m89]
  #pragma unroll
  for (int m = 0; m < 4; ++m) {
    int grb = bm * 128 + wm * 64 + m * 16 + fq * 4;
    #pragma unroll
    for (int n = 0; n < 4; ++n) {
      int gc = bn * 128 + wn * 64 + n * 16 + fr;
      float bv = bias[gc];
      #pragma unroll
      for (int j = 0; j < 4; ++j) {
        int gr = grb + j;
        size_t idx = (size_t)gr * N + gc;
        float v = acc[m][n][j] + bv;
        if (EPI == 0) {
          ((u16*)Cout)[idx] = f2b(v);
        } else if (EPI == 1) {
          // gelu tanh-approx == v * sigmoid(2*0.7978845608*(v + 0.044715 v^3))
          float g = v / (1.f + __expf(-1.5957691216f * (v + 0.044715f * v * v * v)));
          ((u16*)Cout)[idx] = f2b(g);
        } else {
          int b = gr >> 10;
          float mv = mods[b * D6_ + mod_off + gc];
          ((float*)Cout)[idx] = resid[idx] + mv * v;
        }
      }
    }
  }
}

// ---------------- flash-style attention, fp32 math from bf16 qkv.
// block: 256 thr, one (b, h, 32-query tile); loops 32-key tiles with online softmax.
__global__ __launch_bounds__(256, 2) void attn_kernel(const u16* __restrict__ qkv,
                                                      u16* __restrict__ attn_out) {
  int qt = blockIdx.x, h = blockIdx.y, b = blockIdx.z;
  int tid = threadIdx.x;
  __shared__ float Qs[32][73];
  __shared__ float Ks[32][73];
  __shared__ float Vs[32][73];
  __shared__ float S[32][33];
  __shared__ float mrow[32], lrow[32], arow[32];
  const size_t base = (size_t)b * T_ * D3_;
  const int hoff = h * HD_;
  int q0 = qt * 32;

  for (int u = tid; u < 32 * HD_; u += 256) {
    int r = u / HD_, d = u % HD_;
    Qs[r][d] = b2f(qkv[base + (size_t)(q0 + r) * D3_ + hoff + d]);
  }
  if (tid < 32) { mrow[tid] = -1e30f; lrow[tid] = 0.f; }
  __syncthreads();

  // PV accumulator lives in registers: thread owns q = tid>>3, d in [dbase, dbase+9)
  int qown = tid >> 3;
  int dbase = (tid & 7) * 9;
  float accr[9] = {0.f,0.f,0.f,0.f,0.f,0.f,0.f,0.f,0.f};

  const float scale = 0.11785113019775793f;   // 1/sqrt(72)
  for (int kt = 0; kt < 32; ++kt) {
    int k0 = kt * 32;
    for (int u = tid; u < 32 * HD_; u += 256) {
      int r = u / HD_, d = u % HD_;
      size_t rowb = base + (size_t)(k0 + r) * D3_;
      Ks[r][d] = b2f(qkv[rowb + D_ + hoff + d]);
      Vs[r][d] = b2f(qkv[rowb + 2 * D_ + hoff + d]);
    }
    __syncthreads();
    // scores: thread -> k = tid&31, 4 query rows qb+{0,8,16,24}
    {
      int k = tid & 31, qb = tid >> 5;
      float s0 = 0, s1 = 0, s2 = 0, s3 = 0;
      for (int d = 0; d < HD_; ++d) {
        float kv = Ks[k][d];
        s0 += Qs[qb][d] * kv;
        s1 += Qs[qb + 8][d] * kv;
        s2 += Qs[qb + 16][d] * kv;
        s3 += Qs[qb + 24][d] * kv;
      }
      S[qb][k] = s0 * scale;  S[qb + 8][k] = s1 * scale;
      S[qb + 16][k] = s2 * scale; S[qb + 24][k] = s3 * scale;
    }
    __syncthreads();
    if (tid < 32) {                       // online-softmax bookkeeping, 1 thr / row
      int q = tid;
      float mx = mrow[q];
      #pragma unroll
      for (int k = 0; k < 32; ++k) mx = fmaxf(mx, S[q][k]);
      float alpha = __expf(mrow[q] - mx);
      float sum = 0.f;
      #pragma unroll
      for (int k = 0; k < 32; ++k) { float p = __expf(S[q][k] - mx); S[q][k] = p; sum += p; }
      lrow[q] = lrow[q] * alpha + sum;
      mrow[q] = mx;
      arow[q] = alpha;
    }
    __syncthreads();
    {
      float al = arow[qown];
      #pragma unroll
      for (int j = 0; j < 9; ++j) accr[j] *= al;
      for (int k = 0; k < 32; ++k) {
        float p = S[qown][k];
        #pragma unroll
        for (int j = 0; j < 9; ++j) accr[j] += p * Vs[k][dbase + j];
      }
    }
    __syncthreads();
  }
  float linv = 1.f / lrow[qown];
  u16* orow = attn_out + ((size_t)b * T_ + q0 + qown) * D_ + hoff + dbase;
  #pragma unroll
  for (int j = 0; j < 9; ++j) orow[j] = f2b(accr[j] * linv);
}

// ---------------- host orchestration
extern "C" void kernel_launch(void* const* d_in, const int* in_sizes, int n_in,
                              void* d_out, int out_size, void* d_ws, size_t ws_size,
                              hipStream_t stream) {
  const float* x     = (const float*)d_in[0];
  const float* c     = (const float*)d_in[1];
  const float* qkv_w = (const float*)d_in[2];
  const float* qkv_b = (const float*)d_in[3];
  const float* out_w = (const float*)d_in[4];
  const float* out_b = (const float*)d_in[5];
  const float* w1    = (const float*)d_in[6];
  const float* b1    = (const float*)d_in[7];
  const float* w2    = (const float*)d_in[8];
  const float* b2    = (const float*)d_in[9];
  const float* ada_w = (const float*)d_in[10];
  const float* ada_b = (const float*)d_in[11];
  float* out = (float*)d_out;

  char* ws = (char*)d_ws;
  size_t off = 0;
  auto alloc = [&](size_t bytes) { void* p = ws + off; off += (bytes + 255) & ~(size_t)255; return p; };
  float* mods   = (float*)alloc((size_t)B_ * D6_ * 4);
  u16* qkv_wt   = (u16*)alloc((size_t)D_ * D3_ * 2);
  u16* out_wt   = (u16*)alloc((size_t)D_ * D_ * 2);
  u16* w1t      = (u16*)alloc((size_t)D_ * D4_ * 2);
  u16* w2t      = (u16*)alloc((size_t)D4_ * D_ * 2);
  u16* ybuf     = (u16*)alloc((size_t)M_ * D_ * 2);     // reused for y2
  u16* qkvbuf   = (u16*)alloc((size_t)M_ * D3_ * 2);
  u16* attnbuf  = (u16*)alloc((size_t)M_ * D_ * 2);
  float* x1     = (float*)alloc((size_t)M_ * D_ * 4);
  u16* h1       = (u16*)alloc((size_t)M_ * D4_ * 2);
  (void)ws_size; (void)in_sizes; (void)n_in; (void)out_size;

  dim3 tb32(32, 8);
  wconv_kernel<<<dim3(D3_ / 32, D_ / 32), tb32, 0, stream>>>(qkv_w, qkv_wt, D_, D3_);
  wconv_kernel<<<dim3(D_ / 32, D_ / 32), tb32, 0, stream>>>(out_w, out_wt, D_, D_);
  wconv_kernel<<<dim3(D4_ / 32, D_ / 32), tb32, 0, stream>>>(w1, w1t, D_, D4_);
  wconv_kernel<<<dim3(D_ / 32, D4_ / 32), tb32, 0, stream>>>(w2, w2t, D4_, D_);

  mods_kernel<<<dim3(B_, D6_ / 256), 256, 0, stream>>>(c, ada_w, ada_b, mods);

  ln_mod_kernel<<<M_, 256, 0, stream>>>(x, mods, 0, D_, ybuf);

  gemm_kernel<0><<<dim3(M_ / 128, D3_ / 128), 256, 0, stream>>>(
      ybuf, qkv_wt, qkv_b, nullptr, nullptr, 0, qkvbuf, D3_, D_);

  attn_kernel<<<dim3(T_ / 32, H_, B_), 256, 0, stream>>>(qkvbuf, attnbuf);

  gemm_kernel<2><<<dim3(M_ / 128, D_ / 128), 256, 0, stream>>>(
      attnbuf, out_wt, out_b, x, mods, 2 * D_, x1, D_, D_);

  ln_mod_kernel<<<M_, 256, 0, stream>>>(x1, mods, 3 * D_, 4 * D_, ybuf);

  gemm_kernel<1><<<dim3(M_ / 128, D4_ / 128), 256, 0, stream>>>(
      ybuf, w1t, b1, nullptr, nullptr, 0, h1, D4_, D_);

  gemm_kernel<2><<<dim3(M_ / 128, D_ / 128), 256, 0, stream>>>(
      h1, w2t, b2, x1, mods, 5 * D_, out, D_, D4_);
}

// Round 5
// 918.175 us; speedup vs baseline: 3.0384x; 3.0384x over previous
//
#include <hip/hip_runtime.h>

// DiT block fused pipeline for MI355X (gfx950).
// B=8 T=1024 D=1152 H=16 hd=72 E=4.
#define B_ 8
#define T_ 1024
#define D_ 1152
#define H_ 16
#define HD_ 72
#define M_ (B_*T_)      // 8192 rows
#define D3_ (3*D_)      // 3456
#define D4_ (4*D_)      // 4608
#define D6_ (6*D_)      // 6912

#define DP_ 96          // padded head dim for Q/K buffers
#define QB_ 64          // queries per attention block
#define KB_ 32          // keys per tile
#define KP_ 104         // Q/K LDS row pitch (u16) -> 208B, 16B aligned, 2-way banks
#define VP_ 40          // Vt / P LDS row pitch (u16) -> 80B, 16B aligned, 2-way banks

typedef unsigned short u16;
typedef __attribute__((ext_vector_type(4))) float f32x4;
typedef __attribute__((ext_vector_type(4))) unsigned int u32x4;

__device__ __forceinline__ u16 f2b(float f) {           // fp32 -> bf16 RNE
  union { float f; unsigned u; } v; v.f = f;
  unsigned r = v.u + 0x7FFFu + ((v.u >> 16) & 1u);
  return (u16)(r >> 16);
}
__device__ __forceinline__ float b2f(u16 h) {
  union { unsigned u; float f; } v; v.u = ((unsigned)h) << 16;
  return v.f;
}

__device__ __forceinline__ void mfma16x16x32(f32x4& d, u32x4 a, u32x4 b) {
  asm("v_mfma_f32_16x16x32_bf16 %0, %1, %2, %0" : "+v"(d) : "v"(a), "v"(b));
}

__device__ __forceinline__ void load_lds16(const void* g, void* l) {
  __builtin_amdgcn_global_load_lds((const __attribute__((address_space(1))) void*)g,
                                   (__attribute__((address_space(3))) void*)l, 16, 0, 0);
}

// ---------------- weight transpose + bf16 convert:  W[K][N] f32 -> Wt[N][K] bf16
__global__ __launch_bounds__(256) void wconv_kernel(const float* __restrict__ W,
                                                    u16* __restrict__ Wt, int K, int N) {
  __shared__ float tile[32][33];
  int k0 = blockIdx.y * 32, n0 = blockIdx.x * 32;
  int tx = threadIdx.x, ty = threadIdx.y;   // 32 x 8
  #pragma unroll
  for (int i = 0; i < 32; i += 8)
    tile[ty + i][tx] = W[(size_t)(k0 + ty + i) * N + n0 + tx];
  __syncthreads();
  #pragma unroll
  for (int i = 0; i < 32; i += 8)
    Wt[(size_t)(n0 + ty + i) * K + k0 + tx] = f2b(tile[tx][ty + i]);
}

// ---------------- mods = silu(c) @ ada_w + ada_b   -> [B][6D] f32
__global__ __launch_bounds__(256) void mods_kernel(const float* __restrict__ c,
                                                   const float* __restrict__ ada_w,
                                                   const float* __restrict__ ada_b,
                                                   float* __restrict__ mods) {
  int b = blockIdx.x;
  int j = blockIdx.y * 256 + threadIdx.x;
  __shared__ float sc[D_];
  for (int d = threadIdx.x; d < D_; d += 256) {
    float v = c[b * D_ + d];
    sc[d] = v / (1.f + __expf(-v));
  }
  __syncthreads();
  float acc = ada_b[j];
  for (int k = 0; k < D_; ++k) acc += sc[k] * ada_w[(size_t)k * D6_ + j];
  mods[b * D6_ + j] = acc;
}

// ---------------- LayerNorm + modulate -> bf16 activations
__global__ __launch_bounds__(256) void ln_mod_kernel(const float* __restrict__ x,
                                                     const float* __restrict__ mods,
                                                     int shift_off, int scale_off,
                                                     u16* __restrict__ y) {
  int row = blockIdx.x;          // 0..8191
  int b = row >> 10;
  int tid = threadIdx.x;
  const float* xr = x + (size_t)row * D_;
  float s = 0.f, ss = 0.f;
  for (int d = tid; d < D_; d += 256) { float v = xr[d]; s += v; ss += v * v; }
  #pragma unroll
  for (int o = 32; o > 0; o >>= 1) { s += __shfl_down(s, o); ss += __shfl_down(ss, o); }
  __shared__ float red[2][4];
  int wid = tid >> 6, lane = tid & 63;
  if (lane == 0) { red[0][wid] = s; red[1][wid] = ss; }
  __syncthreads();
  __shared__ float stat[2];
  if (tid == 0) {
    float S = red[0][0] + red[0][1] + red[0][2] + red[0][3];
    float SS = red[1][0] + red[1][1] + red[1][2] + red[1][3];
    float mu = S * (1.f / D_);
    float var = SS * (1.f / D_) - mu * mu;
    stat[0] = mu; stat[1] = rsqrtf(var + 1e-6f);
  }
  __syncthreads();
  float mu = stat[0], inv = stat[1];
  const float* sh = mods + b * D6_ + shift_off;
  const float* scl = mods + b * D6_ + scale_off;
  u16* yr = y + (size_t)row * D_;
  for (int d = tid; d < D_; d += 256) {
    float v = (xr[d] - mu) * inv;
    yr[d] = f2b(v * (1.f + scl[d]) + sh[d]);
  }
}

// ---------------- bf16 MFMA GEMM, 128x128x32 tiles, m97 structure.
// A[M][K] bf16 row-major, Bt[N][K] bf16 row-major (i.e. B transposed).
// EPI: 0 = acc+bias -> bf16 ; 1 = gelu_tanh(acc+bias) -> bf16 ;
//      2 = resid + mod*(acc+bias) -> f32 ; 3 = qkv split into q/k/v head buffers
template<int EPI>
__global__ __launch_bounds__(256, 2)
void gemm_kernel(const u16* __restrict__ A, const u16* __restrict__ Bt,
                 const float* __restrict__ bias, const float* __restrict__ resid,
                 const float* __restrict__ mods, int mod_off,
                 void* __restrict__ Cout, u16* __restrict__ q_out,
                 u16* __restrict__ k_out, u16* __restrict__ v_out, int N, int K) {
  __shared__ __align__(16) u16 As[128 * 32];
  __shared__ __align__(16) u16 Bs[128 * 32];
  int bm = blockIdx.x, bn = blockIdx.y;
  int tid = threadIdx.x;
  int lane = tid & 63;
  int wid = tid >> 6;
  int wm = wid >> 1, wn = wid & 1;          // 2x2 wave grid, each wave 64x64
  int fr = lane & 15, fq = lane >> 4;

  f32x4 acc[4][4] = {};

  const char* Ab = (const char*)A + (size_t)bm * 128 * K * 2;
  const char* Bb = (const char*)Bt + (size_t)bn * 128 * K * 2;
  int o0 = tid * 16;                        // per-lane byte offset in 8KB tile
  int r0 = o0 >> 6, cb = o0 & 63;           // tile row / byte-in-row
  const char* Ag0 = Ab + (size_t)r0 * (K * 2) + cb;
  const char* Ag1 = Ab + (size_t)(r0 + 64) * (K * 2) + cb;
  const char* Bg0 = Bb + (size_t)r0 * (K * 2) + cb;
  const char* Bg1 = Bb + (size_t)(r0 + 64) * (K * 2) + cb;
  u16* Al0 = As + (o0 >> 1);
  u16* Al1 = As + ((o0 + 4096) >> 1);
  u16* Bl0 = Bs + (o0 >> 1);
  u16* Bl1 = Bs + ((o0 + 4096) >> 1);

  const u32x4* pA = ((const u32x4*)As) + (wm * 64 + fr) * 4 + fq;
  const u32x4* pB = ((const u32x4*)Bs) + (wn * 64 + fr) * 4 + fq;

  for (int k0 = 0; k0 < K; k0 += 32) {
    size_t kb = (size_t)k0 * 2;
    load_lds16(Ag0 + kb, Al0);
    load_lds16(Ag1 + kb, Al1);
    load_lds16(Bg0 + kb, Bl0);
    load_lds16(Bg1 + kb, Bl1);
    __syncthreads();
    u32x4 af[4], bfr[4];
    #pragma unroll
    for (int m = 0; m < 4; ++m) af[m] = pA[m * 64];
    #pragma unroll
    for (int n = 0; n < 4; ++n) bfr[n] = pB[n * 64];
    #pragma unroll
    for (int m = 0; m < 4; ++m)
      #pragma unroll
      for (int n = 0; n < 4; ++n)
        mfma16x16x32(acc[m][n], af[m], bfr[n]);
    __syncthreads();
  }

  // epilogue: C/D layout col=lane&15 (fr), row=4*(lane>>4)+j (fq*4+j)   [m89]
  #pragma unroll
  for (int m = 0; m < 4; ++m) {
    int grb = bm * 128 + wm * 64 + m * 16 + fq * 4;
    #pragma unroll
    for (int n = 0; n < 4; ++n) {
      int gc = bn * 128 + wn * 64 + n * 16 + fr;
      float bv = bias[gc];
      #pragma unroll
      for (int j = 0; j < 4; ++j) {
        int gr = grb + j;
        size_t idx = (size_t)gr * N + gc;
        float v = acc[m][n][j] + bv;
        if (EPI == 0) {
          ((u16*)Cout)[idx] = f2b(v);
        } else if (EPI == 1) {
          // gelu tanh-approx == v * sigmoid(2*0.7978845608*(v + 0.044715 v^3))
          float g = v / (1.f + __expf(-1.5957691216f * (v + 0.044715f * v * v * v)));
          ((u16*)Cout)[idx] = f2b(g);
        } else if (EPI == 2) {
          int b = gr >> 10;
          float mv = mods[b * D6_ + mod_off + gc];
          ((float*)Cout)[idx] = resid[idx] + mv * v;
        } else {
          // qkv split: gc -> (sec, h, d); gr -> (b, t)
          int b = gr >> 10, t = gr & 1023;
          int sec = gc / D_;
          int rem = gc - sec * D_;
          int h = rem / HD_;
          int d = rem - h * HD_;
          size_t hbrow = ((size_t)b * H_ + h) * T_ + t;
          u16 bv16 = f2b(v);
          if (sec == 0)      q_out[hbrow * DP_ + d] = bv16;
          else if (sec == 1) k_out[hbrow * DP_ + d] = bv16;
          else               v_out[hbrow * HD_ + d] = bv16;
        }
      }
    }
  }
}

// ---------------- MFMA flash attention.
// Block: 256 thr = 4 waves; wave w owns 16 queries. Streams 32-key tiles.
// Swapped QK^T (mfma(K,Q)) so S cols = queries -> wave-parallel softmax via shfl.
__global__ __launch_bounds__(256, 2) void attn_mfma_kernel(
    const u16* __restrict__ qbuf, const u16* __restrict__ kbuf,
    const u16* __restrict__ vbuf, u16* __restrict__ attn_out) {
  int qt = blockIdx.x, h = blockIdx.y, b = blockIdx.z;
  int tid = threadIdx.x;
  int lane = tid & 63, wid = tid >> 6;
  int fr = lane & 15, g = lane >> 4;

  __shared__ __align__(16) u16 Qs[QB_ * KP_];
  __shared__ __align__(16) u16 Ks[KB_ * KP_];
  __shared__ __align__(16) u16 Vt[80 * VP_];
  __shared__ __align__(16) u16 Ps[4][16 * VP_];
  __shared__ float arow[4][16];
  __shared__ float lrow[4][16];

  const size_t hb = ((size_t)b * H_ + h) * T_;
  int q0 = qt * QB_;

  // stage Q: 64 rows x 96 u16 (12 x 16B chunks per row)
  for (int c = tid; c < QB_ * 12; c += 256) {
    int r = c / 12, c16 = c % 12;
    *(u32x4*)((char*)Qs + r * (KP_ * 2) + c16 * 16) =
        *(const u32x4*)((const char*)(qbuf + (hb + q0 + r) * DP_) + c16 * 16);
  }
  if (tid < 320) Vt[72 * VP_ + tid] = 0;   // zero pad rows 72..79 (8 x 40 u16)
  __syncthreads();

  u32x4 qf[3];                              // wave's Q fragments (queries q0+16w..+15)
  #pragma unroll
  for (int ds = 0; ds < 3; ++ds)
    qf[ds] = *(const u32x4*)((const char*)Qs + (wid * 16 + fr) * (KP_ * 2) + ds * 64 + g * 16);

  float mreg = -1e30f, lreg = 0.f;
  f32x4 acc[5] = {};
  const float scale = 0.11785113019775793f; // 1/sqrt(72)

  for (int kt = 0; kt < T_ / KB_; ++kt) {
    int k0 = kt * KB_;
    // stage K (32 rows x 96 u16)
    for (int c = tid; c < KB_ * 12; c += 256) {
      int r = c / 12, c16 = c % 12;
      *(u32x4*)((char*)Ks + r * (KP_ * 2) + c16 * 16) =
          *(const u32x4*)((const char*)(kbuf + (hb + k0 + r) * DP_) + c16 * 16);
    }
    // stage V transposed: V[32][72] -> Vt[72][32]
    for (int u = tid; u < KB_ * HD_; u += 256) {
      int r = u / HD_, d = u - r * HD_;
      Vt[d * VP_ + r] = vbuf[(hb + k0 + r) * HD_ + d];
    }
    __syncthreads();

    // S = K · Q^T : D rows = keys (4g+j), cols = queries (fr)
    f32x4 s0 = {}, s1 = {};
    #pragma unroll
    for (int ds = 0; ds < 3; ++ds) {
      u32x4 k0f = *(const u32x4*)((const char*)Ks + fr * (KP_ * 2) + ds * 64 + g * 16);
      u32x4 k1f = *(const u32x4*)((const char*)Ks + (16 + fr) * (KP_ * 2) + ds * 64 + g * 16);
      mfma16x16x32(s0, k0f, qf[ds]);
      mfma16x16x32(s1, k1f, qf[ds]);
    }
    // online softmax, per-lane q = fr
    float mt = -1e30f;
    #pragma unroll
    for (int j = 0; j < 4; ++j) {
      s0[j] *= scale; s1[j] *= scale;
      mt = fmaxf(mt, fmaxf(s0[j], s1[j]));
    }
    mt = fmaxf(mt, __shfl_xor(mt, 16));
    mt = fmaxf(mt, __shfl_xor(mt, 32));
    float mnew = fmaxf(mreg, mt);
    float alpha = __expf(mreg - mnew);
    float psum = 0.f;
    u16* prow = &Ps[wid][fr * VP_];
    #pragma unroll
    for (int j = 0; j < 4; ++j) {
      float p0 = __expf(s0[j] - mnew);
      float p1 = __expf(s1[j] - mnew);
      psum += p0 + p1;
      prow[4 * g + j] = f2b(p0);            // keys 0..15
      prow[16 + 4 * g + j] = f2b(p1);       // keys 16..31
    }
    psum += __shfl_xor(psum, 16);
    psum += __shfl_xor(psum, 32);
    lreg = lreg * alpha + psum;
    mreg = mnew;
    if (g == 0) arow[wid][fr] = alpha;
    asm volatile("s_waitcnt lgkmcnt(0)" ::: "memory");
    // rescale acc rows q = 4g+j
    float al[4];
    #pragma unroll
    for (int j = 0; j < 4; ++j) al[j] = arow[wid][4 * g + j];
    #pragma unroll
    for (int n = 0; n < 5; ++n)
      #pragma unroll
      for (int j = 0; j < 4; ++j) acc[n][j] *= al[j];
    // PV: A = P (q x 32 keys), B = Vt rows = d
    u32x4 pf = *(const u32x4*)((const char*)&Ps[wid][0] + fr * (VP_ * 2) + g * 16);
    #pragma unroll
    for (int n = 0; n < 5; ++n) {
      u32x4 vf = *(const u32x4*)((const char*)Vt + (n * 16 + fr) * (VP_ * 2) + g * 16);
      mfma16x16x32(acc[n], pf, vf);
    }
    __syncthreads();
  }

  if (g == 0) lrow[wid][fr] = lreg;
  asm volatile("s_waitcnt lgkmcnt(0)" ::: "memory");
  float linv[4];
  #pragma unroll
  for (int j = 0; j < 4; ++j) linv[j] = 1.f / lrow[wid][4 * g + j];
  size_t orow_base = (size_t)b * T_ + q0 + wid * 16;
  #pragma unroll
  for (int n = 0; n < 5; ++n) {
    int d = n * 16 + fr;
    if (d < HD_) {
      #pragma unroll
      for (int j = 0; j < 4; ++j)
        attn_out[(orow_base + 4 * g + j) * D_ + h * HD_ + d] = f2b(acc[n][j] * linv[j]);
    }
  }
}

// ---------------- host orchestration
extern "C" void kernel_launch(void* const* d_in, const int* in_sizes, int n_in,
                              void* d_out, int out_size, void* d_ws, size_t ws_size,
                              hipStream_t stream) {
  const float* x     = (const float*)d_in[0];
  const float* c     = (const float*)d_in[1];
  const float* qkv_w = (const float*)d_in[2];
  const float* qkv_b = (const float*)d_in[3];
  const float* out_w = (const float*)d_in[4];
  const float* out_b = (const float*)d_in[5];
  const float* w1    = (const float*)d_in[6];
  const float* b1    = (const float*)d_in[7];
  const float* w2    = (const float*)d_in[8];
  const float* b2    = (const float*)d_in[9];
  const float* ada_w = (const float*)d_in[10];
  const float* ada_b = (const float*)d_in[11];
  float* out = (float*)d_out;

  char* ws = (char*)d_ws;
  size_t off = 0;
  auto alloc = [&](size_t bytes) { void* p = ws + off; off += (bytes + 255) & ~(size_t)255; return p; };
  float* mods   = (float*)alloc((size_t)B_ * D6_ * 4);
  u16* qkv_wt   = (u16*)alloc((size_t)D_ * D3_ * 2);
  u16* out_wt   = (u16*)alloc((size_t)D_ * D_ * 2);
  u16* w1t      = (u16*)alloc((size_t)D_ * D4_ * 2);
  u16* w2t      = (u16*)alloc((size_t)D4_ * D_ * 2);
  u16* ybuf     = (u16*)alloc((size_t)M_ * D_ * 2);     // reused for y2
  u16* qbuf     = (u16*)alloc((size_t)B_ * H_ * T_ * DP_ * 2);
  u16* kbuf     = (u16*)alloc((size_t)B_ * H_ * T_ * DP_ * 2);
  u16* vbuf     = (u16*)alloc((size_t)B_ * H_ * T_ * HD_ * 2);
  u16* attnbuf  = (u16*)alloc((size_t)M_ * D_ * 2);
  float* x1     = (float*)alloc((size_t)M_ * D_ * 4);
  u16* h1       = (u16*)alloc((size_t)M_ * D4_ * 2);
  (void)ws_size; (void)in_sizes; (void)n_in; (void)out_size;

  dim3 tb32(32, 8);
  wconv_kernel<<<dim3(D3_ / 32, D_ / 32), tb32, 0, stream>>>(qkv_w, qkv_wt, D_, D3_);
  wconv_kernel<<<dim3(D_ / 32, D_ / 32), tb32, 0, stream>>>(out_w, out_wt, D_, D_);
  wconv_kernel<<<dim3(D4_ / 32, D_ / 32), tb32, 0, stream>>>(w1, w1t, D_, D4_);
  wconv_kernel<<<dim3(D_ / 32, D4_ / 32), tb32, 0, stream>>>(w2, w2t, D4_, D_);

  mods_kernel<<<dim3(B_, D6_ / 256), 256, 0, stream>>>(c, ada_w, ada_b, mods);

  ln_mod_kernel<<<M_, 256, 0, stream>>>(x, mods, 0, D_, ybuf);

  // zero Q/K pad columns (d = 72..95 must contribute 0 to QK^T)
  hipMemsetAsync(qbuf, 0, (size_t)B_ * H_ * T_ * DP_ * 2, stream);
  hipMemsetAsync(kbuf, 0, (size_t)B_ * H_ * T_ * DP_ * 2, stream);

  gemm_kernel<3><<<dim3(M_ / 128, D3_ / 128), 256, 0, stream>>>(
      ybuf, qkv_wt, qkv_b, nullptr, nullptr, 0, nullptr, qbuf, kbuf, vbuf, D3_, D_);

  attn_mfma_kernel<<<dim3(T_ / QB_, H_, B_), 256, 0, stream>>>(qbuf, kbuf, vbuf, attnbuf);

  gemm_kernel<2><<<dim3(M_ / 128, D_ / 128), 256, 0, stream>>>(
      attnbuf, out_wt, out_b, x, mods, 2 * D_, x1, nullptr, nullptr, nullptr, D_, D_);

  ln_mod_kernel<<<M_, 256, 0, stream>>>(x1, mods, 3 * D_, 4 * D_, ybuf);

  gemm_kernel<1><<<dim3(M_ / 128, D4_ / 128), 256, 0, stream>>>(
      ybuf, w1t, b1, nullptr, nullptr, 0, h1, nullptr, nullptr, nullptr, D4_, D_);

  gemm_kernel<2><<<dim3(M_ / 128, D_ / 128), 256, 0, stream>>>(
      h1, w2t, b2, x1, mods, 5 * D_, out, nullptr, nullptr, nullptr, D_, D4_);
}

// Round 6
// 792.994 us; speedup vs baseline: 3.5180x; 1.1579x over previous
//
#include <hip/hip_runtime.h>

// DiT block fused pipeline for MI355X (gfx950).
// B=8 T=1024 D=1152 H=16 hd=72 E=4.
#define B_ 8
#define T_ 1024
#define D_ 1152
#define H_ 16
#define HD_ 72
#define M_ (B_*T_)      // 8192 rows
#define D3_ (3*D_)      // 3456
#define D4_ (4*D_)      // 4608
#define D6_ (6*D_)      // 6912

#define DP_ 96          // padded head dim for Q/K buffers
#define QB_ 64          // queries per attention block
#define KB_ 32          // keys per tile
#define KP_ 104         // K LDS row pitch (u16) -> 208B, 16B aligned, 2-way banks
#define VP_ 40          // Vt / P LDS row pitch (u16) -> 80B, 16B aligned, 2-way banks
#define NT_ (T_/KB_)    // 32 key tiles

typedef unsigned short u16;
typedef __attribute__((ext_vector_type(4))) float f32x4;
typedef __attribute__((ext_vector_type(4))) unsigned int u32x4;

__device__ __forceinline__ u16 f2b(float f) {           // fp32 -> bf16 RNE
  union { float f; unsigned u; } v; v.f = f;
  unsigned r = v.u + 0x7FFFu + ((v.u >> 16) & 1u);
  return (u16)(r >> 16);
}
__device__ __forceinline__ float b2f(u16 h) {
  union { unsigned u; float f; } v; v.u = ((unsigned)h) << 16;
  return v.f;
}

__device__ __forceinline__ void mfma16x16x32(f32x4& d, u32x4 a, u32x4 b) {
  asm("v_mfma_f32_16x16x32_bf16 %0, %1, %2, %0" : "+v"(d) : "v"(a), "v"(b));
}

__device__ __forceinline__ void load_lds16(const void* g, void* l) {
  __builtin_amdgcn_global_load_lds((const __attribute__((address_space(1))) void*)g,
                                   (__attribute__((address_space(3))) void*)l, 16, 0, 0);
}

// ---------------- weight transpose + bf16 convert:  W[K][N] f32 -> Wt[N][K] bf16
__global__ __launch_bounds__(256) void wconv_kernel(const float* __restrict__ W,
                                                    u16* __restrict__ Wt, int K, int N) {
  __shared__ float tile[32][33];
  int k0 = blockIdx.y * 32, n0 = blockIdx.x * 32;
  int tx = threadIdx.x, ty = threadIdx.y;   // 32 x 8
  #pragma unroll
  for (int i = 0; i < 32; i += 8)
    tile[ty + i][tx] = W[(size_t)(k0 + ty + i) * N + n0 + tx];
  __syncthreads();
  #pragma unroll
  for (int i = 0; i < 32; i += 8)
    Wt[(size_t)(n0 + ty + i) * K + k0 + tx] = f2b(tile[tx][ty + i]);
}

// ---------------- mods = silu(c) @ ada_w + ada_b   -> [B][6D] f32
__global__ __launch_bounds__(256) void mods_kernel(const float* __restrict__ c,
                                                   const float* __restrict__ ada_w,
                                                   const float* __restrict__ ada_b,
                                                   float* __restrict__ mods) {
  int b = blockIdx.x;
  int j = blockIdx.y * 256 + threadIdx.x;
  __shared__ float sc[D_];
  for (int d = threadIdx.x; d < D_; d += 256) {
    float v = c[b * D_ + d];
    sc[d] = v / (1.f + __expf(-v));
  }
  __syncthreads();
  float acc = ada_b[j];
  for (int k = 0; k < D_; ++k) acc += sc[k] * ada_w[(size_t)k * D6_ + j];
  mods[b * D6_ + j] = acc;
}

// ---------------- LayerNorm + modulate -> bf16 activations
__global__ __launch_bounds__(256) void ln_mod_kernel(const float* __restrict__ x,
                                                     const float* __restrict__ mods,
                                                     int shift_off, int scale_off,
                                                     u16* __restrict__ y) {
  int row = blockIdx.x;          // 0..8191
  int b = row >> 10;
  int tid = threadIdx.x;
  const float* xr = x + (size_t)row * D_;
  float s = 0.f, ss = 0.f;
  for (int d = tid; d < D_; d += 256) { float v = xr[d]; s += v; ss += v * v; }
  #pragma unroll
  for (int o = 32; o > 0; o >>= 1) { s += __shfl_down(s, o); ss += __shfl_down(ss, o); }
  __shared__ float red[2][4];
  int wid = tid >> 6, lane = tid & 63;
  if (lane == 0) { red[0][wid] = s; red[1][wid] = ss; }
  __syncthreads();
  __shared__ float stat[2];
  if (tid == 0) {
    float S = red[0][0] + red[0][1] + red[0][2] + red[0][3];
    float SS = red[1][0] + red[1][1] + red[1][2] + red[1][3];
    float mu = S * (1.f / D_);
    float var = SS * (1.f / D_) - mu * mu;
    stat[0] = mu; stat[1] = rsqrtf(var + 1e-6f);
  }
  __syncthreads();
  float mu = stat[0], inv = stat[1];
  const float* sh = mods + b * D6_ + shift_off;
  const float* scl = mods + b * D6_ + scale_off;
  u16* yr = y + (size_t)row * D_;
  for (int d = tid; d < D_; d += 256) {
    float v = (xr[d] - mu) * inv;
    yr[d] = f2b(v * (1.f + scl[d]) + sh[d]);
  }
}

// ---------------- bf16 MFMA GEMM, 128x128x32 tiles, m97 structure.
// A[M][K] bf16 row-major, Bt[N][K] bf16 row-major (i.e. B transposed).
// EPI: 0 = acc+bias -> bf16 ; 1 = gelu_tanh(acc+bias) -> bf16 ;
//      2 = resid + mod*(acc+bias) -> f32 ; 3 = qkv split into q/k/v head buffers
//      (EPI 3 stores V pre-transposed [b][h][d][t] for the attention PV step)
template<int EPI>
__global__ __launch_bounds__(256, 2)
void gemm_kernel(const u16* __restrict__ A, const u16* __restrict__ Bt,
                 const float* __restrict__ bias, const float* __restrict__ resid,
                 const float* __restrict__ mods, int mod_off,
                 void* __restrict__ Cout, u16* __restrict__ q_out,
                 u16* __restrict__ k_out, u16* __restrict__ v_out, int N, int K) {
  __shared__ __align__(16) u16 As[128 * 32];
  __shared__ __align__(16) u16 Bs[128 * 32];
  int bm = blockIdx.x, bn = blockIdx.y;
  int tid = threadIdx.x;
  int lane = tid & 63;
  int wid = tid >> 6;
  int wm = wid >> 1, wn = wid & 1;          // 2x2 wave grid, each wave 64x64
  int fr = lane & 15, fq = lane >> 4;

  f32x4 acc[4][4] = {};

  const char* Ab = (const char*)A + (size_t)bm * 128 * K * 2;
  const char* Bb = (const char*)Bt + (size_t)bn * 128 * K * 2;
  int o0 = tid * 16;                        // per-lane byte offset in 8KB tile
  int r0 = o0 >> 6, cb = o0 & 63;           // tile row / byte-in-row
  const char* Ag0 = Ab + (size_t)r0 * (K * 2) + cb;
  const char* Ag1 = Ab + (size_t)(r0 + 64) * (K * 2) + cb;
  const char* Bg0 = Bb + (size_t)r0 * (K * 2) + cb;
  const char* Bg1 = Bb + (size_t)(r0 + 64) * (K * 2) + cb;
  u16* Al0 = As + (o0 >> 1);
  u16* Al1 = As + ((o0 + 4096) >> 1);
  u16* Bl0 = Bs + (o0 >> 1);
  u16* Bl1 = Bs + ((o0 + 4096) >> 1);

  const u32x4* pA = ((const u32x4*)As) + (wm * 64 + fr) * 4 + fq;
  const u32x4* pB = ((const u32x4*)Bs) + (wn * 64 + fr) * 4 + fq;

  for (int k0 = 0; k0 < K; k0 += 32) {
    size_t kb = (size_t)k0 * 2;
    load_lds16(Ag0 + kb, Al0);
    load_lds16(Ag1 + kb, Al1);
    load_lds16(Bg0 + kb, Bl0);
    load_lds16(Bg1 + kb, Bl1);
    __syncthreads();
    u32x4 af[4], bfr[4];
    #pragma unroll
    for (int m = 0; m < 4; ++m) af[m] = pA[m * 64];
    #pragma unroll
    for (int n = 0; n < 4; ++n) bfr[n] = pB[n * 64];
    #pragma unroll
    for (int m = 0; m < 4; ++m)
      #pragma unroll
      for (int n = 0; n < 4; ++n)
        mfma16x16x32(acc[m][n], af[m], bfr[n]);
    __syncthreads();
  }

  // epilogue: C/D layout col=lane&15 (fr), row=4*(lane>>4)+j (fq*4+j)   [m89]
  #pragma unroll
  for (int m = 0; m < 4; ++m) {
    int grb = bm * 128 + wm * 64 + m * 16 + fq * 4;
    #pragma unroll
    for (int n = 0; n < 4; ++n) {
      int gc = bn * 128 + wn * 64 + n * 16 + fr;
      float bv = bias[gc];
      #pragma unroll
      for (int j = 0; j < 4; ++j) {
        int gr = grb + j;
        size_t idx = (size_t)gr * N + gc;
        float v = acc[m][n][j] + bv;
        if (EPI == 0) {
          ((u16*)Cout)[idx] = f2b(v);
        } else if (EPI == 1) {
          // gelu tanh-approx == v * sigmoid(2*0.7978845608*(v + 0.044715 v^3))
          float g = v / (1.f + __expf(-1.5957691216f * (v + 0.044715f * v * v * v)));
          ((u16*)Cout)[idx] = f2b(g);
        } else if (EPI == 2) {
          int b = gr >> 10;
          float mv = mods[b * D6_ + mod_off + gc];
          ((float*)Cout)[idx] = resid[idx] + mv * v;
        } else {
          // qkv split: gc -> (sec, h, d); gr -> (b, t)
          int b = gr >> 10, t = gr & 1023;
          int sec = gc / D_;
          int rem = gc - sec * D_;
          int h = rem / HD_;
          int d = rem - h * HD_;
          u16 bv16 = f2b(v);
          if (sec == 0)      q_out[(((size_t)b * H_ + h) * T_ + t) * DP_ + d] = bv16;
          else if (sec == 1) k_out[(((size_t)b * H_ + h) * T_ + t) * DP_ + d] = bv16;
          else               v_out[(((size_t)b * H_ + h) * HD_ + d) * T_ + t] = bv16;
        }
      }
    }
  }
}

// ---------------- MFMA flash attention, v2.
// 4 waves x 16 queries; 32-key tiles; double-buffered K/V staging (1 barrier/tile).
// Q fragments loaded global->reg directly. V arrives pre-transposed [b][h][d][t],
// staged with 16B vector loads (no scalar transpose, ~no bank conflicts).
__global__ __launch_bounds__(256, 2) void attn_mfma_kernel(
    const u16* __restrict__ qbuf, const u16* __restrict__ kbuf,
    const u16* __restrict__ vbuf, u16* __restrict__ attn_out) {
  int qt = blockIdx.x, h = blockIdx.y, b = blockIdx.z;
  int tid = threadIdx.x;
  int lane = tid & 63, wid = tid >> 6;
  int fr = lane & 15, g = lane >> 4;

  __shared__ __align__(16) u16 Ks[2][KB_ * KP_];   // 2 x 32 x 104
  __shared__ __align__(16) u16 Vt[2][80 * VP_];    // 2 x 80 x 40 (rows = d, cols = key)
  __shared__ __align__(16) u16 Ps[4][16 * VP_];
  __shared__ float arow[4][16];
  __shared__ float lrow[4][16];

  const size_t hb = ((size_t)b * H_ + h) * T_;
  const size_t vh = ((size_t)b * H_ + h) * HD_ * T_;
  int q0 = qt * QB_;

  // Q fragments direct from global (rows contiguous 96 u16, 16B-aligned)
  u32x4 qf[3];
  {
    const u16* qrow = qbuf + (hb + q0 + wid * 16 + fr) * DP_;
    #pragma unroll
    for (int ds = 0; ds < 3; ++ds)
      qf[ds] = *(const u32x4*)(qrow + ds * 32 + g * 8);
  }

  // zero Vt pad rows d=72..79 (both buffers, once)
  for (int i2 = tid; i2 < 640; i2 += 256)
    Vt[i2 / 320][72 * VP_ + (i2 % 320)] = 0;

  // staging: K tile (32 rows x 12 16B-chunks) + V tile (72 d-rows x 4 16B-chunks)
  auto stage = [&](int kt, int p) {
    int k0 = kt * KB_;
    const u16* kg = kbuf + (hb + k0) * DP_;
    const u16* vg = vbuf + vh + k0;
    for (int c = tid; c < 384 + 288; c += 256) {
      if (c < 384) {
        int r = c / 12, c16 = c % 12;
        *(u32x4*)(Ks[p] + r * KP_ + c16 * 8) = *(const u32x4*)(kg + (size_t)r * DP_ + c16 * 8);
      } else {
        int c2 = c - 384;
        int d = c2 >> 2, cc = c2 & 3;
        *(u32x4*)(Vt[p] + d * VP_ + cc * 8) = *(const u32x4*)(vg + (size_t)d * T_ + cc * 8);
      }
    }
  };

  stage(0, 0);
  __syncthreads();

  float mreg = -1e30f, lreg = 0.f;
  f32x4 acc[5] = {};
  const float scale = 0.11785113019775793f; // 1/sqrt(72)

  for (int kt = 0; kt < NT_; ++kt) {
    int p = kt & 1;
    if (kt + 1 < NT_) stage(kt + 1, p ^ 1);   // prefetch into other buffer

    // S = K · Q^T : rows = keys (4g+j), cols = queries (fr)
    f32x4 s0 = {}, s1 = {};
    #pragma unroll
    for (int ds = 0; ds < 3; ++ds) {
      u32x4 k0f = *(const u32x4*)(Ks[p] + fr * KP_ + ds * 32 + g * 8);
      u32x4 k1f = *(const u32x4*)(Ks[p] + (16 + fr) * KP_ + ds * 32 + g * 8);
      mfma16x16x32(s0, k0f, qf[ds]);
      mfma16x16x32(s1, k1f, qf[ds]);
    }
    // online softmax, per-lane q = fr
    float mt = -1e30f;
    #pragma unroll
    for (int j = 0; j < 4; ++j) {
      s0[j] *= scale; s1[j] *= scale;
      mt = fmaxf(mt, fmaxf(s0[j], s1[j]));
    }
    mt = fmaxf(mt, __shfl_xor(mt, 16));
    mt = fmaxf(mt, __shfl_xor(mt, 32));
    float mnew = fmaxf(mreg, mt);
    float alpha = __expf(mreg - mnew);
    float psum = 0.f;
    u16* prow = &Ps[wid][fr * VP_];
    #pragma unroll
    for (int j = 0; j < 4; ++j) {
      float p0 = __expf(s0[j] - mnew);
      float p1 = __expf(s1[j] - mnew);
      psum += p0 + p1;
      prow[4 * g + j] = f2b(p0);            // keys 0..15
      prow[16 + 4 * g + j] = f2b(p1);       // keys 16..31
    }
    psum += __shfl_xor(psum, 16);
    psum += __shfl_xor(psum, 32);
    lreg = lreg * alpha + psum;
    mreg = mnew;
    if (g == 0) arow[wid][fr] = alpha;
    asm volatile("s_waitcnt lgkmcnt(0)" ::: "memory");
    // rescale acc rows q = 4g+j
    float al[4];
    #pragma unroll
    for (int j = 0; j < 4; ++j) al[j] = arow[wid][4 * g + j];
    #pragma unroll
    for (int n = 0; n < 5; ++n)
      #pragma unroll
      for (int j = 0; j < 4; ++j) acc[n][j] *= al[j];
    // PV: A = P (q x 32 keys), B = Vt rows = d
    u32x4 pf = *(const u32x4*)((const char*)&Ps[wid][0] + fr * (VP_ * 2) + g * 16);
    #pragma unroll
    for (int n = 0; n < 5; ++n) {
      u32x4 vf = *(const u32x4*)(Vt[p] + (n * 16 + fr) * VP_ + g * 8);
      mfma16x16x32(acc[n], pf, vf);
    }
    __syncthreads();   // buf p reads done; next iter may overwrite it
  }

  if (g == 0) lrow[wid][fr] = lreg;
  asm volatile("s_waitcnt lgkmcnt(0)" ::: "memory");
  float linv[4];
  #pragma unroll
  for (int j = 0; j < 4; ++j) linv[j] = 1.f / lrow[wid][4 * g + j];
  size_t orow_base = (size_t)b * T_ + q0 + wid * 16;
  #pragma unroll
  for (int n = 0; n < 5; ++n) {
    int d = n * 16 + fr;
    if (d < HD_) {
      #pragma unroll
      for (int j = 0; j < 4; ++j)
        attn_out[(orow_base + 4 * g + j) * D_ + h * HD_ + d] = f2b(acc[n][j] * linv[j]);
    }
  }
}

// ---------------- host orchestration
extern "C" void kernel_launch(void* const* d_in, const int* in_sizes, int n_in,
                              void* d_out, int out_size, void* d_ws, size_t ws_size,
                              hipStream_t stream) {
  const float* x     = (const float*)d_in[0];
  const float* c     = (const float*)d_in[1];
  const float* qkv_w = (const float*)d_in[2];
  const float* qkv_b = (const float*)d_in[3];
  const float* out_w = (const float*)d_in[4];
  const float* out_b = (const float*)d_in[5];
  const float* w1    = (const float*)d_in[6];
  const float* b1    = (const float*)d_in[7];
  const float* w2    = (const float*)d_in[8];
  const float* b2    = (const float*)d_in[9];
  const float* ada_w = (const float*)d_in[10];
  const float* ada_b = (const float*)d_in[11];
  float* out = (float*)d_out;

  char* ws = (char*)d_ws;
  size_t off = 0;
  auto alloc = [&](size_t bytes) { void* p = ws + off; off += (bytes + 255) & ~(size_t)255; return p; };
  float* mods   = (float*)alloc((size_t)B_ * D6_ * 4);
  u16* qkv_wt   = (u16*)alloc((size_t)D_ * D3_ * 2);
  u16* out_wt   = (u16*)alloc((size_t)D_ * D_ * 2);
  u16* w1t      = (u16*)alloc((size_t)D_ * D4_ * 2);
  u16* w2t      = (u16*)alloc((size_t)D4_ * D_ * 2);
  u16* ybuf     = (u16*)alloc((size_t)M_ * D_ * 2);     // reused for y2
  u16* qbuf     = (u16*)alloc((size_t)B_ * H_ * T_ * DP_ * 2);
  u16* kbuf     = (u16*)alloc((size_t)B_ * H_ * T_ * DP_ * 2);
  u16* vbuf     = (u16*)alloc((size_t)B_ * H_ * HD_ * T_ * 2);  // [b][h][d][t]
  u16* attnbuf  = (u16*)alloc((size_t)M_ * D_ * 2);
  float* x1     = (float*)alloc((size_t)M_ * D_ * 4);
  u16* h1       = (u16*)alloc((size_t)M_ * D4_ * 2);
  (void)ws_size; (void)in_sizes; (void)n_in; (void)out_size;

  dim3 tb32(32, 8);
  wconv_kernel<<<dim3(D3_ / 32, D_ / 32), tb32, 0, stream>>>(qkv_w, qkv_wt, D_, D3_);
  wconv_kernel<<<dim3(D_ / 32, D_ / 32), tb32, 0, stream>>>(out_w, out_wt, D_, D_);
  wconv_kernel<<<dim3(D4_ / 32, D_ / 32), tb32, 0, stream>>>(w1, w1t, D_, D4_);
  wconv_kernel<<<dim3(D_ / 32, D4_ / 32), tb32, 0, stream>>>(w2, w2t, D4_, D_);

  mods_kernel<<<dim3(B_, D6_ / 256), 256, 0, stream>>>(c, ada_w, ada_b, mods);

  ln_mod_kernel<<<M_, 256, 0, stream>>>(x, mods, 0, D_, ybuf);

  // zero Q/K pad columns (d = 72..95 must contribute 0 to QK^T)
  hipMemsetAsync(qbuf, 0, (size_t)B_ * H_ * T_ * DP_ * 2, stream);
  hipMemsetAsync(kbuf, 0, (size_t)B_ * H_ * T_ * DP_ * 2, stream);

  gemm_kernel<3><<<dim3(M_ / 128, D3_ / 128), 256, 0, stream>>>(
      ybuf, qkv_wt, qkv_b, nullptr, nullptr, 0, nullptr, qbuf, kbuf, vbuf, D3_, D_);

  attn_mfma_kernel<<<dim3(T_ / QB_, H_, B_), 256, 0, stream>>>(qbuf, kbuf, vbuf, attnbuf);

  gemm_kernel<2><<<dim3(M_ / 128, D_ / 128), 256, 0, stream>>>(
      attnbuf, out_wt, out_b, x, mods, 2 * D_, x1, nullptr, nullptr, nullptr, D_, D_);

  ln_mod_kernel<<<M_, 256, 0, stream>>>(x1, mods, 3 * D_, 4 * D_, ybuf);

  gemm_kernel<1><<<dim3(M_ / 128, D4_ / 128), 256, 0, stream>>>(
      ybuf, w1t, b1, nullptr, nullptr, 0, h1, nullptr, nullptr, nullptr, D4_, D_);

  gemm_kernel<2><<<dim3(M_ / 128, D_ / 128), 256, 0, stream>>>(
      h1, w2t, b2, x1, mods, 5 * D_, out, nullptr, nullptr, nullptr, D_, D4_);
}